// Round 8
// baseline (221.971 us; speedup 1.0000x reference)
//
#include <hip/hip_runtime.h>
#include <hip/hip_bf16.h>

using u16 = unsigned short;

static constexpr int N  = 2;
static constexpr int C  = 64;
static constexpr int H  = 256;
static constexpr int W  = 256;
static constexpr int Hd = 128;
static constexpr int Wd = 128;
static constexpr int Cm = 64;
static constexpr int KK = 25;
static constexpr int C2 = 256;
static constexpr int OC = 64;
static constexpr int HWP  = H * W;    // 65536
static constexpr int HDWD = Hd * Wd;  // 16384

__device__ __forceinline__ float bflo(unsigned u) { return __uint_as_float(u << 16); }
__device__ __forceinline__ float bfhi(unsigned u) { return __uint_as_float(u & 0xffff0000u); }
__device__ __forceinline__ unsigned pack2(float a, float b) {
    __hip_bfloat16 ha = __float2bfloat16(a), hb = __float2bfloat16(b);
    union { __hip_bfloat16 h; u16 u; } ua{ha}, ub{hb};
    return (unsigned)ua.u | ((unsigned)ub.u << 16);
}

// ---------------- Kernel A: 1x1 down conv -> k1 PIXEL-MAJOR [n][px][cm] -----
// (R6-benched version: 256-px tile, grid 512)
__global__ __launch_bounds__(256) void kA_down(const float* __restrict__ x,
                                               const float* __restrict__ w,
                                               const float* __restrict__ b,
                                               u16* __restrict__ k1) {
    __shared__ u16   xt[64][256];    // bf16 x tile [c][px_local]   32 KB
    __shared__ float wt[64][66];     // w transposed [c][cm]
    const int tid = threadIdx.x;
    const int pg0 = blockIdx.x * 256;
    const int n   = pg0 >> 16;
    const int px0 = pg0 & (HWP - 1);

#pragma unroll
    for (int i = 0; i < 16; ++i) {
        int e  = i * 256 + tid;
        int cm = e >> 6, c = e & 63;
        wt[c][cm] = w[e];
    }
    const float* xb = x + (size_t)n * C * HWP + px0;
#pragma unroll
    for (int i = 0; i < 16; ++i) {
        int flat = i * 256 + tid;
        int row  = flat >> 6;
        int col4 = flat & 63;
        float4 v = *(const float4*)(xb + (size_t)row * HWP + col4 * 4);
        uint2 p;
        p.x = pack2(v.x, v.y);
        p.y = pack2(v.z, v.w);
        *(uint2*)&xt[row][col4 * 4] = p;
    }
    __syncthreads();

    const int cg  = tid & 7;
    const int pxg = tid >> 3;
    float acc[8][8];
#pragma unroll
    for (int j = 0; j < 8; ++j) {
        float bj = b[cg * 8 + j];
#pragma unroll
        for (int p = 0; p < 8; ++p) acc[j][p] = bj;
    }
#pragma unroll 8
    for (int c = 0; c < 64; ++c) {
        uint4 xv = *(const uint4*)&xt[c][pxg * 8];
        float xs[8] = {bflo(xv.x), bfhi(xv.x), bflo(xv.y), bfhi(xv.y),
                       bflo(xv.z), bfhi(xv.z), bflo(xv.w), bfhi(xv.w)};
        float2 w01 = *(const float2*)&wt[c][cg * 8 + 0];
        float2 w23 = *(const float2*)&wt[c][cg * 8 + 2];
        float2 w45 = *(const float2*)&wt[c][cg * 8 + 4];
        float2 w67 = *(const float2*)&wt[c][cg * 8 + 6];
        float wv[8] = {w01.x, w01.y, w23.x, w23.y, w45.x, w45.y, w67.x, w67.y};
#pragma unroll
        for (int j = 0; j < 8; ++j)
#pragma unroll
            for (int p = 0; p < 8; ++p) acc[j][p] = fmaf(wv[j], xs[p], acc[j][p]);
    }
#pragma unroll
    for (int p = 0; p < 8; ++p) {
        uint4 o;
        o.x = pack2(acc[0][p], acc[1][p]);
        o.y = pack2(acc[2][p], acc[3][p]);
        o.z = pack2(acc[4][p], acc[5][p]);
        o.w = pack2(acc[6][p], acc[7][p]);
        *(uint4*)(k1 + ((size_t)pg0 + pxg * 8 + p) * 64 + cg * 8) = o;
    }
}

// ---- Kernel W: repack enc weights  ew[kk][cm][3][3] -> ewt[tap][cm][kk] ----
__global__ __launch_bounds__(256) void kW_repack(const float* __restrict__ ew,
                                                 float* __restrict__ ewt) {
    int i = blockIdx.x * 256 + threadIdx.x;
    if (i < 25 * 64 * 9) {
        int tap = i % 9;
        int r   = i / 9;
        int cm  = r % 64;
        int kk  = r / 64;
        ewt[(tap * 64 + cm) * 25 + kk] = ew[i];
    }
}

// -------- Kernel B: 3x3 s2 enc conv (64->25) + softmax -> ksm fp32 ----------
// grid(512) x block(512): 64 px (lanes) x 8 cm-groups of 8 (waves).
// 4096 waves total = 16 waves/CU. 9 uint4 loads/thread, clamped + masked.
__global__ __launch_bounds__(512) void kB_enc(const u16* __restrict__ k1,
                                              const float* __restrict__ ewt,
                                              const float* __restrict__ eb,
                                              float* __restrict__ ksm) {
    __shared__ float red[8][64][27];   // [group][px][kk], odd pitch -> no conflicts
    const int tid  = threadIdx.x;
    const int lane = tid & 63;
    const int g    = tid >> 6;               // 0..7, wave-uniform
    const int pix = blockIdx.x * 64 + lane;
    const int n   = pix >> 14;
    const int hd  = __builtin_amdgcn_readfirstlane((pix >> 7) & 127);
    const int wd  = pix & 127;
    const int cm0 = g * 8;

    const u16* kbase = k1 + (size_t)n * HWP * 64;

    // 9 tap loads (clamped addresses), masked after
    uint4 t[9];
#pragma unroll
    for (int tp = 0; tp < 9; ++tp) {
        int dy = tp / 3, dx = tp - dy * 3;
        int y  = 2 * hd + dy - 1;
        int yc = max(y, 0);                  // y <= 255 always
        int xx = 2 * wd + dx - 1;
        int xc = max(xx, 0);                 // xx <= 255 always
        t[tp] = *(const uint4*)(kbase + ((size_t)(yc * W + xc)) * 64 + cm0);
    }
    const uint4 z4 = make_uint4(0u, 0u, 0u, 0u);
    if (hd == 0) { t[0] = z4; t[1] = z4; t[2] = z4; }   // uniform
    if (wd == 0) { t[0] = z4; t[3] = z4; t[6] = z4; }   // lane 0 only

    float acc[25];
#pragma unroll
    for (int kk = 0; kk < 25; ++kk) acc[kk] = 0.f;

#pragma unroll
    for (int tp = 0; tp < 9; ++tp) {
        float v[8] = {bflo(t[tp].x), bfhi(t[tp].x), bflo(t[tp].y), bfhi(t[tp].y),
                      bflo(t[tp].z), bfhi(t[tp].z), bflo(t[tp].w), bfhi(t[tp].w)};
        const float* wp = ewt + (tp * 64 + cm0) * 25;   // uniform, contiguous
#pragma unroll
        for (int i = 0; i < 8; ++i)
#pragma unroll
            for (int kk = 0; kk < 25; ++kk)
                acc[kk] = fmaf(v[i], wp[i * 25 + kk], acc[kk]);
    }
#pragma unroll
    for (int kk = 0; kk < 25; ++kk) red[g][lane][kk] = acc[kk];
    __syncthreads();

    if (tid < 64) {
        float lg[25];
        float m = -1e30f;
#pragma unroll
        for (int kk = 0; kk < 25; ++kk) {
            float s = eb[kk];
#pragma unroll
            for (int gg = 0; gg < 8; ++gg) s += red[gg][tid][kk];
            lg[kk] = s;
            m = fmaxf(m, s);
        }
        float ssum = 0.f;
#pragma unroll
        for (int kk = 0; kk < 25; ++kk) { lg[kk] = __expf(lg[kk] - m); ssum += lg[kk]; }
        float inv = 1.f / ssum;
        float* ob = ksm + (size_t)n * KK * HDWD + hd * Wd + wd;
#pragma unroll
        for (int kk = 0; kk < 25; ++kk) ob[(size_t)kk * HDWD] = lg[kk] * inv;
    }
}

// ---- Kernel C: weighted reassembly -> out2 (N,256,Hd,Wd) bf16 --------------
__global__ __launch_bounds__(256) void kC_reassemble(const float* __restrict__ x,
                                                     const float* __restrict__ ksm,
                                                     u16* __restrict__ out2) {
    __shared__ float xts[6 * 272];
    const int tid = threadIdx.x;
    const int b   = blockIdx.x;
    const int cchunk = b & 7;
    const int hdt = (b >> 3) & 31;
    const int q   = (b >> 8) & 3;
    const int n   = b >> 10;
    const int hd0 = hdt * 4;
    const int wv   = tid >> 6;
    const int lane = tid & 63;
    const int hd  = hd0 + wv;
    const int wd0 = lane * 2;
    const int w0  = ((wv & 1) << 7) + wd0;
    const int lr0 = wv >> 1;
    const int y0  = q * 64 + (hd0 >> 1) - 2;
    const int c0  = cchunk * 8;

    const float* kb = ksm + (size_t)n * KK * HDWD + hd * Wd + wd0;
    float2 kw[25];
#pragma unroll
    for (int kk = 0; kk < 25; ++kk) kw[kk] = *(const float2*)(kb + (size_t)kk * HDWD);

    const int s0 = tid, s1 = tid + 256;
    const int r0s = s0 / 68, c40 = s0 - r0s * 68;
    const int r1s = s1 / 68, c41 = s1 - r1s * 68;
    const int ya = y0 + r0s, yb = y0 + r1s;
    const bool v0 = (c40 >= 1) & (c40 <= 64) & (ya >= 0) & (ya < H);
    const bool v1 = (s1 < 408) & (c41 >= 1) & (c41 <= 64) & (yb >= 0) & (yb < H);
    const float* xn = x + (size_t)n * C * HWP + (size_t)c0 * HWP;
    const float* g0 = xn + (size_t)ya * W + (c40 - 1) * 4;
    const float* g1 = xn + (size_t)yb * W + (c41 - 1) * 4;

    const float4 z = make_float4(0.f, 0.f, 0.f, 0.f);
    float4 p0 = v0 ? *(const float4*)g0 : z;
    float4 p1 = v1 ? *(const float4*)g1 : z;

    for (int ci = 0; ci < 8; ++ci) {
        __syncthreads();
        *(float4*)&xts[4 * s0] = p0;
        if (s1 < 408) *(float4*)&xts[4 * s1] = p1;
        __syncthreads();

        if (ci < 7) {
            p0 = v0 ? *(const float4*)(g0 + (size_t)(ci + 1) * HWP) : z;
            p1 = v1 ? *(const float4*)(g1 + (size_t)(ci + 1) * HWP) : z;
        }

        float a0 = 0.f, a1 = 0.f;
#pragma unroll
        for (int i = 0; i < 5; ++i) {
            const float* rr = &xts[(lr0 + i) * 272 + w0 + 2];
            float2 r0 = *(const float2*)(rr + 0);
            float2 r1 = *(const float2*)(rr + 2);
            float2 r2 = *(const float2*)(rr + 4);
            float f[6] = {r0.x, r0.y, r1.x, r1.y, r2.x, r2.y};
#pragma unroll
            for (int j = 0; j < 5; ++j) {
                const float2 kv = kw[i * 5 + j];
                a0 = fmaf(f[j + 0], kv.x, a0);
                a1 = fmaf(f[j + 1], kv.y, a1);
            }
        }
        const int c2 = 4 * (c0 + ci) + q;
        u16* op = out2 + ((size_t)(n * C2 + c2) * Hd + hd) * Wd + wd0;
        *(unsigned*)op = pack2(a0, a1);
    }
}

// ---- Kernel D: 1x1 out conv (256 -> 64) -> d_out fp32 ----------------------
// (R6-benched version: grid(32,16), thread = 4 px x 4 co, 8-deep batches)
__global__ __launch_bounds__(256) void kD_out(const u16* __restrict__ out2,
                                              const float* __restrict__ ow,
                                              const float* __restrict__ ob,
                                              float* __restrict__ out) {
    const int co0 = blockIdx.y * 4;
    const int pg  = blockIdx.x * 256 + threadIdx.x;
    const int n   = pg >> 12;
    const int hw  = (pg << 2) & (HDWD - 1);
    const u16* ib = out2 + (size_t)n * C2 * HDWD + hw;

    float acc[4][4];
#pragma unroll
    for (int j = 0; j < 4; ++j) {
        float bj = ob[co0 + j];
#pragma unroll
        for (int p = 0; p < 4; ++p) acc[j][p] = bj;
    }
    for (int c2 = 0; c2 < 256; c2 += 8) {
        uint2 u[8];
#pragma unroll
        for (int t = 0; t < 8; ++t)
            u[t] = *(const uint2*)(ib + (size_t)(c2 + t) * HDWD);
#pragma unroll
        for (int t = 0; t < 8; ++t) {
            float xs[4] = {bflo(u[t].x), bfhi(u[t].x), bflo(u[t].y), bfhi(u[t].y)};
#pragma unroll
            for (int j = 0; j < 4; ++j) {
                float wv = ow[(co0 + j) * 256 + c2 + t];
#pragma unroll
                for (int p = 0; p < 4; ++p) acc[j][p] = fmaf(wv, xs[p], acc[j][p]);
            }
        }
    }
#pragma unroll
    for (int j = 0; j < 4; ++j) {
        float* op = out + (size_t)(n * OC + co0 + j) * HDWD + hw;
        *(float4*)op = make_float4(acc[j][0], acc[j][1], acc[j][2], acc[j][3]);
    }
}

extern "C" void kernel_launch(void* const* d_in, const int* in_sizes, int n_in,
                              void* d_out, int out_size, void* d_ws, size_t ws_size,
                              hipStream_t stream) {
    const float* x  = (const float*)d_in[0];
    const float* dw = (const float*)d_in[1];
    const float* db = (const float*)d_in[2];
    const float* ew = (const float*)d_in[3];
    const float* eb = (const float*)d_in[4];
    const float* ow = (const float*)d_in[5];
    const float* ob = (const float*)d_in[6];
    float* out = (float*)d_out;

    char* ws = (char*)d_ws;
    u16*   k1   = (u16*)ws;                               // [n][px][cm] 16.8 MB
    float* ksm  = (float*)(ws + 16777216);                // 3.3 MB
    u16*   out2 = (u16*)(ws + 16777216 + 3276800);        // 16.8 MB
    float* ewt  = (float*)out2;   // kW writes, kB reads, kC clobbers after

    kW_repack<<<dim3(57), dim3(256), 0, stream>>>(ew, ewt);
    kA_down<<<dim3(512), dim3(256), 0, stream>>>(x, dw, db, k1);
    kB_enc<<<dim3(512), dim3(512), 0, stream>>>(k1, ewt, eb, ksm);
    kC_reassemble<<<dim3(2048), dim3(256), 0, stream>>>(x, ksm, out2);
    kD_out<<<dim3(32, 16), dim3(256), 0, stream>>>(out2, ow, ob, out);
}

// Round 9
// 164.782 us; speedup vs baseline: 1.3471x; 1.3471x over previous
//
#include <hip/hip_runtime.h>
#include <hip/hip_bf16.h>

using u16 = unsigned short;
typedef __attribute__((ext_vector_type(8))) short bf16x8;
typedef __attribute__((ext_vector_type(4))) float f32x4;

static constexpr int N  = 2;
static constexpr int C  = 64;
static constexpr int H  = 256;
static constexpr int W  = 256;
static constexpr int Hd = 128;
static constexpr int Wd = 128;
static constexpr int KK = 25;
static constexpr int C2 = 256;
static constexpr int OC = 64;
static constexpr int HWP  = H * W;    // 65536
static constexpr int HDWD = Hd * Wd;  // 16384

__device__ __forceinline__ float bflo(unsigned u) { return __uint_as_float(u << 16); }
__device__ __forceinline__ float bfhi(unsigned u) { return __uint_as_float(u & 0xffff0000u); }
__device__ __forceinline__ unsigned pack2(float a, float b) {
    __hip_bfloat16 ha = __float2bfloat16(a), hb = __float2bfloat16(b);
    union { __hip_bfloat16 h; u16 u; } ua{ha}, ub{hb};
    return (unsigned)ua.u | ((unsigned)ub.u << 16);
}
__device__ __forceinline__ u16 f2bf(float f) {
    union { __hip_bfloat16 h; u16 u; } v{__float2bfloat16(f)};
    return v.u;
}

// ---------------- Kernel A: 1x1 down conv -> k1 PIXEL-MAJOR [n][px][cm] -----
__global__ __launch_bounds__(256) void kA_down(const float* __restrict__ x,
                                               const float* __restrict__ w,
                                               const float* __restrict__ b,
                                               u16* __restrict__ k1) {
    __shared__ u16   xt[64][256];
    __shared__ float wt[64][66];
    const int tid = threadIdx.x;
    const int pg0 = blockIdx.x * 256;
    const int n   = pg0 >> 16;
    const int px0 = pg0 & (HWP - 1);

#pragma unroll
    for (int i = 0; i < 16; ++i) {
        int e  = i * 256 + tid;
        int cm = e >> 6, c = e & 63;
        wt[c][cm] = w[e];
    }
    const float* xb = x + (size_t)n * C * HWP + px0;
#pragma unroll
    for (int i = 0; i < 16; ++i) {
        int flat = i * 256 + tid;
        int row  = flat >> 6;
        int col4 = flat & 63;
        float4 v = *(const float4*)(xb + (size_t)row * HWP + col4 * 4);
        uint2 p;
        p.x = pack2(v.x, v.y);
        p.y = pack2(v.z, v.w);
        *(uint2*)&xt[row][col4 * 4] = p;
    }
    __syncthreads();

    const int cg  = tid & 7;
    const int pxg = tid >> 3;
    float acc[8][8];
#pragma unroll
    for (int j = 0; j < 8; ++j) {
        float bj = b[cg * 8 + j];
#pragma unroll
        for (int p = 0; p < 8; ++p) acc[j][p] = bj;
    }
#pragma unroll 8
    for (int c = 0; c < 64; ++c) {
        uint4 xv = *(const uint4*)&xt[c][pxg * 8];
        float xs[8] = {bflo(xv.x), bfhi(xv.x), bflo(xv.y), bfhi(xv.y),
                       bflo(xv.z), bfhi(xv.z), bflo(xv.w), bfhi(xv.w)};
        float2 w01 = *(const float2*)&wt[c][cg * 8 + 0];
        float2 w23 = *(const float2*)&wt[c][cg * 8 + 2];
        float2 w45 = *(const float2*)&wt[c][cg * 8 + 4];
        float2 w67 = *(const float2*)&wt[c][cg * 8 + 6];
        float wv[8] = {w01.x, w01.y, w23.x, w23.y, w45.x, w45.y, w67.x, w67.y};
#pragma unroll
        for (int j = 0; j < 8; ++j)
#pragma unroll
            for (int p = 0; p < 8; ++p) acc[j][p] = fmaf(wv[j], xs[p], acc[j][p]);
    }
#pragma unroll
    for (int p = 0; p < 8; ++p) {
        uint4 o;
        o.x = pack2(acc[0][p], acc[1][p]);
        o.y = pack2(acc[2][p], acc[3][p]);
        o.z = pack2(acc[4][p], acc[5][p]);
        o.w = pack2(acc[6][p], acc[7][p]);
        *(uint4*)(k1 + ((size_t)pg0 + pxg * 8 + p) * 64 + cg * 8) = o;
    }
}

// ---- Kernel W2: pack enc weights into MFMA B-fragment layout (bf16) --------
// bfr[ft][lane][8] u16, ft = s*2 + t; s = k-step (tap*2+h), t = n-tile.
// B[n = lane&15][k_local = (lane>>4)*8 + j], k = tap*64 + 32h + 8q + j -> cm.
__global__ __launch_bounds__(256) void kW2_pack(const float* __restrict__ ew,
                                                u16* __restrict__ bfr) {
    int idx = blockIdx.x * 256 + threadIdx.x;   // over 36*64 = 2304
    if (idx < 2304) {
        int l  = idx & 63;
        int ft = idx >> 6;
        int t  = ft & 1, s = ft >> 1;
        int tap = s >> 1, h = s & 1;
        int c = l & 15, q = l >> 4;
        int kk = t * 16 + c;
        u16 o[8];
#pragma unroll
        for (int j = 0; j < 8; ++j) {
            int cm = 32 * h + 8 * q + j;
            float v = (kk < 25) ? ew[(kk * 64 + cm) * 9 + tap] : 0.f;
            o[j] = f2bf(v);
        }
        *(uint4*)(bfr + (size_t)idx * 8) = *(uint4*)o;
    }
}

// -------- Kernel B2: enc conv as MFMA GEMM + in-register softmax ------------
// grid(512): block = one hd row x 64 wd (4 waves x 16-px m-tiles).
__global__ __launch_bounds__(256) void kB2_enc(const u16* __restrict__ k1,
                                               const u16* __restrict__ bfr,
                                               const float* __restrict__ eb,
                                               float* __restrict__ ksm) {
    __shared__ u16 tile[3 * 130 * 72];   // [y][x][cm], pitch 72 u16 = 144 B
    const int tid = threadIdx.x;
    const int b   = blockIdx.x;
    const int half = b & 1;
    const int hd   = (b >> 1) & 127;
    const int n    = b >> 8;
    const int w0 = half * 64;
    const int xb = 2 * w0 - 1;
    const int y0 = 2 * hd - 1;
    const u16* kb = k1 + (size_t)n * HWP * 64;

    // stage 3 rows x 129 px x 64 cm (zero-filled at borders)
    for (int r = 0; r < 13; ++r) {
        int f = r * 256 + tid;
        if (f < 3096) {                     // 3*129*8 chunks of 8 cm
            int p  = f >> 3, ch = f & 7;
            int y  = p / 129, xi = p - y * 129;
            int yy = y0 + y, xx = xb + xi;
            uint4 v = make_uint4(0u, 0u, 0u, 0u);
            if (yy >= 0 && xx >= 0 && xx < 256)
                v = *(const uint4*)(kb + ((size_t)(yy * W + xx)) * 64 + ch * 8);
            *(uint4*)&tile[(y * 130 + xi) * 72 + ch * 8] = v;
        }
    }
    __syncthreads();

    const int wv = tid >> 6;           // m-tile 0..3
    const int l  = tid & 63;
    const int c  = l & 15;             // n-index within tile
    const int q  = l >> 4;             // quad

    f32x4 acc0 = {0.f, 0.f, 0.f, 0.f};
    f32x4 acc1 = {0.f, 0.f, 0.f, 0.f};
#pragma unroll
    for (int s = 0; s < 18; ++s) {
        const int tap = s >> 1, h = s & 1;
        const int dy = tap / 3, dx = tap - dy * 3;
        // A-frag: A[m=c][k=q*8+j], m = px in tile, k -> cm = 32h+8q+j
        const u16* ap = &tile[(dy * 130 + 32 * wv + 2 * c + dx) * 72 + 32 * h + 8 * q];
        bf16x8 a  = *(const bf16x8*)ap;
        bf16x8 b0 = *(const bf16x8*)(bfr + ((size_t)(s * 2 + 0) * 64 + l) * 8);
        bf16x8 b1 = *(const bf16x8*)(bfr + ((size_t)(s * 2 + 1) * 64 + l) * 8);
        acc0 = __builtin_amdgcn_mfma_f32_16x16x32_bf16(a, b0, acc0, 0, 0, 0);
        acc1 = __builtin_amdgcn_mfma_f32_16x16x32_bf16(a, b1, acc1, 0, 0, 0);
    }

    // bias
    const float e0 = eb[c];
    const float e1 = eb[min(16 + c, 24)];
    const bool c9 = (c < 9);

    // softmax per px row: row = q*4 + reg, col(lane&15) = kk
#pragma unroll
    for (int r = 0; r < 4; ++r) {
        float l0 = acc0[r] + e0;
        float l1 = c9 ? (acc1[r] + e1) : -1e30f;
        float mx = fmaxf(l0, l1);
#pragma unroll
        for (int d = 1; d < 16; d <<= 1) mx = fmaxf(mx, __shfl_xor(mx, d, 64));
        float x0 = __expf(l0 - mx);
        float x1 = c9 ? __expf(l1 - mx) : 0.f;
        float sm = x0 + x1;
#pragma unroll
        for (int d = 1; d < 16; d <<= 1) sm += __shfl_xor(sm, d, 64);
        float inv = 1.f / sm;
        int wd = w0 + 16 * wv + q * 4 + r;
        float* op = ksm + (size_t)n * KK * HDWD + hd * Wd + wd;
        op[(size_t)c * HDWD] = x0 * inv;
        if (c9) op[(size_t)(16 + c) * HDWD] = x1 * inv;
    }
}

// ---- Kernel C: weighted reassembly -> out2 (N,256,Hd,Wd) bf16 --------------
__global__ __launch_bounds__(256) void kC_reassemble(const float* __restrict__ x,
                                                     const float* __restrict__ ksm,
                                                     u16* __restrict__ out2) {
    __shared__ float xts[6 * 272];
    const int tid = threadIdx.x;
    const int b   = blockIdx.x;
    const int cchunk = b & 7;
    const int hdt = (b >> 3) & 31;
    const int q   = (b >> 8) & 3;
    const int n   = b >> 10;
    const int hd0 = hdt * 4;
    const int wv   = tid >> 6;
    const int lane = tid & 63;
    const int hd  = hd0 + wv;
    const int wd0 = lane * 2;
    const int w0  = ((wv & 1) << 7) + wd0;
    const int lr0 = wv >> 1;
    const int y0  = q * 64 + (hd0 >> 1) - 2;
    const int c0  = cchunk * 8;

    const float* kb = ksm + (size_t)n * KK * HDWD + hd * Wd + wd0;
    float2 kw[25];
#pragma unroll
    for (int kk = 0; kk < 25; ++kk) kw[kk] = *(const float2*)(kb + (size_t)kk * HDWD);

    const int s0 = tid, s1 = tid + 256;
    const int r0s = s0 / 68, c40 = s0 - r0s * 68;
    const int r1s = s1 / 68, c41 = s1 - r1s * 68;
    const int ya = y0 + r0s, yb = y0 + r1s;
    const bool v0 = (c40 >= 1) & (c40 <= 64) & (ya >= 0) & (ya < H);
    const bool v1 = (s1 < 408) & (c41 >= 1) & (c41 <= 64) & (yb >= 0) & (yb < H);
    const float* xn = x + (size_t)n * C * HWP + (size_t)c0 * HWP;
    const float* g0 = xn + (size_t)ya * W + (c40 - 1) * 4;
    const float* g1 = xn + (size_t)yb * W + (c41 - 1) * 4;

    const float4 z = make_float4(0.f, 0.f, 0.f, 0.f);
    float4 p0 = v0 ? *(const float4*)g0 : z;
    float4 p1 = v1 ? *(const float4*)g1 : z;

    for (int ci = 0; ci < 8; ++ci) {
        __syncthreads();
        *(float4*)&xts[4 * s0] = p0;
        if (s1 < 408) *(float4*)&xts[4 * s1] = p1;
        __syncthreads();

        if (ci < 7) {
            p0 = v0 ? *(const float4*)(g0 + (size_t)(ci + 1) * HWP) : z;
            p1 = v1 ? *(const float4*)(g1 + (size_t)(ci + 1) * HWP) : z;
        }

        float a0 = 0.f, a1 = 0.f;
#pragma unroll
        for (int i = 0; i < 5; ++i) {
            const float* rr = &xts[(lr0 + i) * 272 + w0 + 2];
            float2 r0 = *(const float2*)(rr + 0);
            float2 r1 = *(const float2*)(rr + 2);
            float2 r2 = *(const float2*)(rr + 4);
            float f[6] = {r0.x, r0.y, r1.x, r1.y, r2.x, r2.y};
#pragma unroll
            for (int j = 0; j < 5; ++j) {
                const float2 kv = kw[i * 5 + j];
                a0 = fmaf(f[j + 0], kv.x, a0);
                a1 = fmaf(f[j + 1], kv.y, a1);
            }
        }
        const int c2 = 4 * (c0 + ci) + q;
        u16* op = out2 + ((size_t)(n * C2 + c2) * Hd + hd) * Wd + wd0;
        *(unsigned*)op = pack2(a0, a1);
    }
}

// ---- Kernel D: 1x1 out conv (256 -> 64) -> d_out fp32 ----------------------
__global__ __launch_bounds__(256) void kD_out(const u16* __restrict__ out2,
                                              const float* __restrict__ ow,
                                              const float* __restrict__ ob,
                                              float* __restrict__ out) {
    const int co0 = blockIdx.y * 4;
    const int pg  = blockIdx.x * 256 + threadIdx.x;
    const int n   = pg >> 12;
    const int hw  = (pg << 2) & (HDWD - 1);
    const u16* ib = out2 + (size_t)n * C2 * HDWD + hw;

    float acc[4][4];
#pragma unroll
    for (int j = 0; j < 4; ++j) {
        float bj = ob[co0 + j];
#pragma unroll
        for (int p = 0; p < 4; ++p) acc[j][p] = bj;
    }
    for (int c2 = 0; c2 < 256; c2 += 8) {
        uint2 u[8];
#pragma unroll
        for (int t = 0; t < 8; ++t)
            u[t] = *(const uint2*)(ib + (size_t)(c2 + t) * HDWD);
#pragma unroll
        for (int t = 0; t < 8; ++t) {
            float xs[4] = {bflo(u[t].x), bfhi(u[t].x), bflo(u[t].y), bfhi(u[t].y)};
#pragma unroll
            for (int j = 0; j < 4; ++j) {
                float wv = ow[(co0 + j) * 256 + c2 + t];
#pragma unroll
                for (int p = 0; p < 4; ++p) acc[j][p] = fmaf(wv, xs[p], acc[j][p]);
            }
        }
    }
#pragma unroll
    for (int j = 0; j < 4; ++j) {
        float* op = out + (size_t)(n * OC + co0 + j) * HDWD + hw;
        *(float4*)op = make_float4(acc[j][0], acc[j][1], acc[j][2], acc[j][3]);
    }
}

extern "C" void kernel_launch(void* const* d_in, const int* in_sizes, int n_in,
                              void* d_out, int out_size, void* d_ws, size_t ws_size,
                              hipStream_t stream) {
    const float* x  = (const float*)d_in[0];
    const float* dw = (const float*)d_in[1];
    const float* db = (const float*)d_in[2];
    const float* ew = (const float*)d_in[3];
    const float* eb = (const float*)d_in[4];
    const float* ow = (const float*)d_in[5];
    const float* ob = (const float*)d_in[6];
    float* out = (float*)d_out;

    char* ws = (char*)d_ws;
    u16*   k1   = (u16*)ws;                               // [n][px][cm] 16.8 MB
    float* ksm  = (float*)(ws + 16777216);                // 3.3 MB
    u16*   out2 = (u16*)(ws + 16777216 + 3276800);        // 16.8 MB
    // bfr (36 KB, MFMA B-fragments) overlaps out2's head:
    // kW2 writes, kB2 reads, kC clobbers after (stream-ordered, safe).
    u16*   bfr  = out2;

    kW2_pack<<<dim3(9), dim3(256), 0, stream>>>(ew, bfr);
    kA_down<<<dim3(512), dim3(256), 0, stream>>>(x, dw, db, k1);
    kB2_enc<<<dim3(512), dim3(256), 0, stream>>>(k1, bfr, eb, ksm);
    kC_reassemble<<<dim3(2048), dim3(256), 0, stream>>>(x, ksm, out2);
    kD_out<<<dim3(32, 16), dim3(256), 0, stream>>>(out2, ow, ob, out);
}